// Round 7
// baseline (94.998 us; speedup 1.0000x reference)
//
#include <hip/hip_runtime.h>

#define T      64
#define S      32
#define NGRAPH 64
#define NSPLIT 16     // slices per graph -> 1024 blocks
#define NW     4      // waves per block

typedef float v2f __attribute__((ext_vector_type(2)));

// One wave per node: lane = theta, thread holds ALL 32 s-accumulators.
// Exact sigmoids only at the 3 transition slots (4 trans ops), distributed
// branch-free at full rate: val_j = max(clamp01(quadratic(u_j)), clamp01(u_j-1)),
// u_j = j - ceil(f). Quadratic hits (sm, s0, sp) exactly at u=-1,0,1; proven
// w(u)<0 for u<=-2; ramp supplies exact 1.0 for u>=2. Zero atomics, zero
// per-slot transcendentals.
__global__ __launch_bounds__(256, 4) void ect_partial(
    const float* __restrict__ x, const float* __restrict__ v,
    const float* __restrict__ lin, const int* __restrict__ batch,
    float* __restrict__ ws, int n_points)
{
    __shared__ float red[NW * 64 * 34];   // [wave][t][s], stride 34: 2-way banks, b64-aligned

    const int tid = threadIdx.x;
    const int t   = tid & 63;
    const int w   = tid >> 6;
    const int b   = blockIdx.x;
    const int g   = b >> 4;
    const int c   = b & (NSPLIT - 1);

    // lower_bound(g), lower_bound(g+1)
    int lo0 = 0, hi0 = n_points, lo1 = 0, hi1 = n_points;
#pragma unroll 1
    for (int it = 0; it < 17; ++it) {
        const int m0 = (lo0 + hi0) >> 1;
        const int m1 = (lo1 + hi1) >> 1;
        const int b0 = (lo0 < hi0) ? batch[m0] : 0;
        const int b1 = (lo1 < hi1) ? batch[m1] : 0;
        if (lo0 < hi0) { if (b0 <  g) lo0 = m0 + 1; else hi0 = m0; }
        if (lo1 < hi1) { if (b1 <= g) lo1 = m1 + 1; else hi1 = m1; }
    }
    const int len = lo1 - lo0;
    const int n0  = lo0 + (len * c) / NSPLIT;
    const int n1  = lo0 + (len * (c + 1)) / NSPLIT;

    const float lin0     = lin[0];
    const float step     = lin[1] - lin0;
    const float inv_step = 1.0f / step;
    const float K2 = (100.0f * step) * 1.4426950408889634f;   // ~10.24 (log2 units)
    const float r  = __builtin_amdgcn_exp2f(-K2);             // exp(-d)

    const float v0 = v[0 * T + t];
    const float v1 = v[1 * T + t];
    const float v2 = v[2 * T + t];

    v2f acc[16];
#pragma unroll
    for (int p = 0; p < 16; p++) acc[p] = (v2f){0.0f, 0.0f};

#pragma unroll 2
    for (int n = n0 + w; n < n1; n += NW) {
        const float* xp = x + 3 * n;                 // wave-uniform address
        const float nh = xp[0] * v0 + xp[1] * v1 + xp[2] * v2;
        const float f  = (nh - lin0) * inv_step;     // transition position
        const float fs = ceilf(f);
        const float gg = fs - f;                     // [0,1)
        const float e0 = __builtin_amdgcn_exp2f(K2 * (1.0f - gg)); // (1, e^d]
        const float e1 = e0 * r;                     // (r, 1]
        const float e2 = e1 * r;
        const float sm = __builtin_amdgcn_rcpf(1.0f + e0);  // sigma at u=-1
        const float s0 = __builtin_amdgcn_rcpf(1.0f + e1);  // sigma at u=0
        const float sp = __builtin_amdgcn_rcpf(1.0f + e2);  // sigma at u=+1
        const float aq = 0.5f * (sp + sm) - s0;
        const float bq = 0.5f * (sp - sm);
        const v2f av = (v2f){aq, aq}, bv = (v2f){bq, bq}, cv = (v2f){s0, s0};
        const v2f uf = (v2f){-fs, -fs};
        const v2f zero = (v2f){0.0f, 0.0f}, one = (v2f){1.0f, 1.0f};
#pragma unroll
        for (int p = 0; p < 16; p++) {
            const v2f u  = uf + (v2f){(float)(2 * p), (float)(2 * p + 1)};
            const v2f wq = __builtin_elementwise_fma(
                               __builtin_elementwise_fma(av, u, bv), u, cv);
            const v2f m1 = __builtin_elementwise_min(
                               __builtin_elementwise_max(wq, zero), one);
            const v2f m2 = __builtin_elementwise_min(
                               __builtin_elementwise_max(u - one, zero), one);
            acc[p] += __builtin_elementwise_max(m1, m2);
        }
    }

    // combine 4 waves via plain LDS stores (no atomics)
    {
        v2f* row = (v2f*)&red[(w * 64 + t) * 34];   // 8B-aligned (even index)
#pragma unroll
        for (int p = 0; p < 16; p++) row[p] = acc[p];
    }
    __syncthreads();

    float* wsb = ws + (size_t)b * (S * T);
#pragma unroll
    for (int k = 0; k < 8; k++) {
        const int cell = tid + 256 * k;             // coalesced global store
        const int s    = cell >> 6;
        const int tt   = cell & 63;
        float sum = 0.0f;
#pragma unroll
        for (int q = 0; q < NW; q++) sum += red[(q * 64 + tt) * 34 + s];
        wsb[cell] = sum;
    }
}

// Phase 2: out[g][i] = sum of 16 slice partials
__global__ __launch_bounds__(256) void ect_reduce(
    const float* __restrict__ ws, float* __restrict__ out)
{
    const int idx = blockIdx.x * 256 + threadIdx.x;
    const int g   = idx >> 11;
    const int i   = idx & 2047;
    float sum = 0.0f;
#pragma unroll
    for (int c = 0; c < NSPLIT; c++)
        sum += ws[(size_t)(g * NSPLIT + c) * (S * T) + i];
    out[idx] = sum;
}

extern "C" void kernel_launch(void* const* d_in, const int* in_sizes, int n_in,
                              void* d_out, int out_size, void* d_ws, size_t ws_size,
                              hipStream_t stream) {
    const float* x     = (const float*)d_in[0];
    const float* v     = (const float*)d_in[1];
    const float* lin   = (const float*)d_in[2];
    const int*   batch = (const int*)d_in[3];
    float* out = (float*)d_out;
    float* ws  = (float*)d_ws;

    const int n_points = in_sizes[0] / 3;

    ect_partial<<<NGRAPH * NSPLIT, 256, 0, stream>>>(x, v, lin, batch, ws, n_points);
    ect_reduce<<<NGRAPH * S * T / 256, 256, 0, stream>>>(ws, out);
}

// Round 8
// 76.517 us; speedup vs baseline: 1.2415x; 1.2415x over previous
//
#include <hip/hip_runtime.h>

#define T      64
#define S      32
#define NGRAPH 64
#define NSPLIT 16     // slices per graph -> 1024 blocks of 256
#define NW     4

// Delta-encoded ECT. Per (node,theta) the sigmoid profile over s is
// 0..0, sm, s0, sp, 1..1 (exact 3-slot window, R4-validated). Its first
// difference has only 4 nonzero entries -> 4 private-LDS RMWs per node,
// prefix-sum at flush reconstructs all 32 s. Deltas at c<=0 fold into a
// register (value at s=0); c>=32 -> trash bin 0. NO atomics anywhere.
__global__ __launch_bounds__(256, 4) void ect_partial(
    const float* __restrict__ x, const float* __restrict__ v,
    const float* __restrict__ lin, const int* __restrict__ batch,
    float* __restrict__ ws, int n_points)
{
    __shared__ float bins[256 * 33];  // [tid][c]: c=0 trash, 1..31 deltas
    __shared__ float v0s[256];        // per-thread value-at-s0 accumulator

    const int tid  = threadIdx.x;
    const int t    = tid & 63;        // lane == theta
    const int w    = tid >> 6;        // wave id
    const int b    = blockIdx.x;
    const int g    = b >> 4;          // graph
    const int c    = b & (NSPLIT - 1);

    for (int i = tid; i < 256 * 33; i += 256) bins[i] = 0.0f;

    // 32-ary ballot search (all waves redundantly; lanes<32: lb(g), >=32: lb(g+1))
    const int target = (t < 32) ? g : (g + 1);
    const int i32    = t & 31;
    int lo = 0;
    const int strides[3] = {2048, 64, 2};
#pragma unroll
    for (int rnd = 0; rnd < 3; rnd++) {
        const int stride = strides[rnd];
        const int idx  = lo + i32 * stride;
        const int pv   = batch[min(idx, n_points - 1)];
        const bool prd = (idx < n_points) && (pv < target);
        const unsigned long long bal = __ballot(prd);
        const int cnt = __popc((unsigned)(bal >> (t & 32)));
        lo += max(cnt - 1, 0) * stride;
    }
#pragma unroll
    for (int rnd = 0; rnd < 2; rnd++) {         // final range of 2
        const int idx = min(lo, n_points - 1);
        if ((lo < n_points) && (batch[idx] < target)) lo++;
    }
    const int gstart = __shfl(lo, 0);
    const int gend   = __shfl(lo, 32);
    const int len    = gend - gstart;
    const int n0     = gstart + (len * c) / NSPLIT;
    const int n1     = gstart + (len * (c + 1)) / NSPLIT;

    const float lin0     = lin[0];
    const float step     = lin[1] - lin0;
    const float inv_step = 1.0f / step;
    const float K2 = (100.0f * step) * 1.4426950408889634f;   // ~10.24
    const float r  = __builtin_amdgcn_exp2f(-K2);

    const float v0 = v[0 * T + t];
    const float v1 = v[1 * T + t];
    const float v2 = v[2 * T + t];

    float v0acc = 0.0f;
    const int binb = tid * 33;

#pragma unroll 2
    for (int n = n0 + w; n < n1; n += NW) {
        const float* xp = x + 3 * n;            // wave-uniform
        const float nh = fmaf(xp[0], v0, fmaf(xp[1], v1, xp[2] * v2));
        const float f  = (nh - lin0) * inv_step;
        const float fs = ceilf(f);
        const int   ss = (int)fs;
        const float gg = fs - f;                                  // [0,1)
        const float e0 = __builtin_amdgcn_exp2f(fmaf(-K2, gg, K2)); // (1, e^d]
        const float e1 = e0 * r;
        const float e2 = e1 * r;
        const float sm  = __builtin_amdgcn_rcpf(1.0f + e0);
        const float s0v = __builtin_amdgcn_rcpf(1.0f + e1);
        const float sp  = __builtin_amdgcn_rcpf(1.0f + e2);
        // value at s=0 (sum of all deltas with c<=0) -> register
        v0acc += (ss >= 2) ? 0.0f
               : (ss == 1) ? sm
               : (ss == 0) ? s0v
               : (ss == -1) ? sp : 1.0f;
        // 4 deltas at c = ss-1..ss+2; in-range [1,31] -> own bin, else trash 0
        const int p0 = ss - 1, p1 = ss, p2 = ss + 1, p3 = ss + 2;
        const int a0 = binb + (((unsigned)(p0 - 1) < 31u) ? p0 : 0);
        const int a1 = binb + (((unsigned)(p1 - 1) < 31u) ? p1 : 0);
        const int a2 = binb + (((unsigned)(p2 - 1) < 31u) ? p2 : 0);
        const int a3 = binb + (((unsigned)(p3 - 1) < 31u) ? p3 : 0);
        const float r0 = bins[a0], r1 = bins[a1], r2 = bins[a2], r3 = bins[a3];
        bins[a0] = r0 + sm;                     // in-range indices are distinct;
        bins[a1] = r1 + (s0v - sm);             // trash collisions don't matter
        bins[a2] = r2 + (sp - s0v);
        bins[a3] = r3 + (1.0f - sp);
    }

    v0s[tid] = v0acc;
    __syncthreads();

    // merge 4 wave-banks into bank 0
    for (int cell = tid; cell < 64 * 33; cell += 256) {
        const int tt = cell & 63;
        const int cc = cell >> 6;
        const float sum = bins[(0 * 64 + tt) * 33 + cc] + bins[(1 * 64 + tt) * 33 + cc]
                        + bins[(2 * 64 + tt) * 33 + cc] + bins[(3 * 64 + tt) * 33 + cc];
        bins[tt * 33 + cc] = sum;
    }
    if (tid < 64) v0s[tid] += v0s[64 + tid] + v0s[128 + tid] + v0s[192 + tid];
    __syncthreads();

    // prefix over c and coalesced store: wave w covers s in [8w, 8w+8)
    float run = v0s[t];
    const int sbase = 8 * w;
    for (int cc = 1; cc < sbase; cc++) run += bins[t * 33 + cc];
    float* wsb = ws + (size_t)b * (S * T);
#pragma unroll
    for (int j = 0; j < 8; j++) {
        const int s = sbase + j;
        if (s >= 1) run += bins[t * 33 + s];
        wsb[s * T + t] = run;
    }
}

// Phase 2: out[g][cell] = sum of 16 slice partials (plain stores; covers zeroing)
__global__ __launch_bounds__(256) void ect_reduce(
    const float* __restrict__ ws, float* __restrict__ out)
{
    const int idx = blockIdx.x * 256 + threadIdx.x;
    const int g   = idx >> 11;
    const int i   = idx & 2047;
    float sum = 0.0f;
#pragma unroll
    for (int c = 0; c < NSPLIT; c++)
        sum += ws[(size_t)(g * NSPLIT + c) * (S * T) + i];
    out[idx] = sum;
}

extern "C" void kernel_launch(void* const* d_in, const int* in_sizes, int n_in,
                              void* d_out, int out_size, void* d_ws, size_t ws_size,
                              hipStream_t stream) {
    const float* x     = (const float*)d_in[0];
    const float* v     = (const float*)d_in[1];
    const float* lin   = (const float*)d_in[2];
    const int*   batch = (const int*)d_in[3];
    float* out = (float*)d_out;
    float* ws  = (float*)d_ws;

    const int n_points = in_sizes[0] / 3;

    ect_partial<<<NGRAPH * NSPLIT, 256, 0, stream>>>(x, v, lin, batch, ws, n_points);
    ect_reduce<<<NGRAPH * S * T / 256, 256, 0, stream>>>(ws, out);
}